// Round 2
// baseline (1730.117 us; speedup 1.0000x reference)
//
#include <hip/hip_runtime.h>
#include <hip/hip_bf16.h>

#define NWIN 49
#define DIM  128
#define NH   4
#define HD   32

static __device__ __forceinline__ float bf_lo(unsigned u) {
    union { unsigned i; float f; } v; v.i = u << 16; return v.f;
}
static __device__ __forceinline__ float bf_hi(unsigned u) {
    union { unsigned i; float f; } v; v.i = u & 0xffff0000u; return v.f;
}
static __device__ __forceinline__ unsigned short f2bf(float f) {
    union { float f; unsigned i; } v; v.f = f;
    unsigned r = v.i + 0x7fffu + ((v.i >> 16) & 1u);   // round-to-nearest-even
    return (unsigned short)(r >> 16);
}

__global__ __launch_bounds__(256) void winattn_kernel(
    const float* __restrict__ x,        // [B,49,128] fp32
    const float* __restrict__ mask,     // [64,49,49] fp32
    const float* __restrict__ qkv_w,    // [128,384] fp32
    const float* __restrict__ qkv_b,    // [384] fp32
    const float* __restrict__ proj_w,   // [128,128] fp32
    const float* __restrict__ proj_b,   // [128] fp32
    const float* __restrict__ bias_tab, // [169,4] fp32
    const int*   __restrict__ rel_index,// [49,49] int32
    float*       __restrict__ out)      // [B,49,128] fp32
{
    __shared__ __align__(16) unsigned short xs[NWIN * DIM];   // 12544 B (bf16-staged)
    __shared__ __align__(16) float qs[NWIN * HD];             //  6272 B (pre-scaled)
    __shared__ __align__(16) float kT[HD * NWIN];             //  6272 B  kT[d][j]
    __shared__ __align__(16) float vs[NWIN * HD];             //  6272 B
    __shared__ __align__(16) float attn[NWIN * NWIN];         //  9604 B
    __shared__ __align__(16) unsigned short outs[NWIN * DIM]; // 12544 B (bf16-staged)
    // total 53508 B LDS

    const int b = blockIdx.x;
    const int t = threadIdx.x;
    const float scale = 0.17677669529663687f;  // 32^-0.5

    // ---- phase 1: stage x window into LDS as bf16 ----
    {
        const float4* src = (const float4*)(x + (size_t)b * (NWIN * DIM));
        for (int e = t; e < (NWIN * DIM) / 4; e += 256) {
            float4 f = src[e];
            unsigned short u0 = f2bf(f.x), u1 = f2bf(f.y), u2 = f2bf(f.z), u3 = f2bf(f.w);
            uint2 packed;
            packed.x = (unsigned)u0 | ((unsigned)u1 << 16);
            packed.y = (unsigned)u2 | ((unsigned)u3 << 16);
            *(uint2*)(xs + e * 4) = packed;
        }
    }
    __syncthreads();

    const int wmask = b & 63;  // window index within image batch (b % nW)

    for (int h = 0; h < NH; ++h) {
        // ---- phase 2: q,k,v for head h. task = (row i, dim dd) ----
        for (int idx = t; idx < NWIN * HD; idx += 256) {
            const int i = idx >> 5, dd = idx & 31;
            const int cq = h * HD + dd;  // q col; k col = cq+128; v col = cq+256
            float aq = qkv_b[cq];
            float ak = qkv_b[cq + DIM];
            float av = qkv_b[cq + 2 * DIM];
            const float* wbase = qkv_w + cq;
            #pragma unroll 8
            for (int c = 0; c < DIM; c += 4) {
                uint2 xu = *(const uint2*)(xs + i * DIM + c);
                const float x0 = bf_lo(xu.x), x1 = bf_hi(xu.x);
                const float x2 = bf_lo(xu.y), x3 = bf_hi(xu.y);
                const float* wr = wbase + c * 384;
                aq = fmaf(x0, wr[0],    aq);
                aq = fmaf(x1, wr[384],  aq);
                aq = fmaf(x2, wr[768],  aq);
                aq = fmaf(x3, wr[1152], aq);
                ak = fmaf(x0, wr[DIM],         ak);
                ak = fmaf(x1, wr[384 + DIM],   ak);
                ak = fmaf(x2, wr[768 + DIM],   ak);
                ak = fmaf(x3, wr[1152 + DIM],  ak);
                av = fmaf(x0, wr[2 * DIM],        av);
                av = fmaf(x1, wr[384 + 2 * DIM],  av);
                av = fmaf(x2, wr[768 + 2 * DIM],  av);
                av = fmaf(x3, wr[1152 + 2 * DIM], av);
            }
            qs[i * HD + dd] = aq * scale;
            kT[dd * NWIN + i] = ak;       // transposed: conflict-free j-reads later
            vs[i * HD + dd] = av;
        }
        __syncthreads();

        // ---- phase 3: attn logits = q.k + bias + mask ----
        for (int idx = t; idx < NWIN * NWIN; idx += 256) {
            const int i = idx / NWIN, j = idx - i * NWIN;
            float acc = 0.f;
            #pragma unroll
            for (int d = 0; d < HD; d += 4) {
                float4 q4 = *(const float4*)(qs + i * HD + d);
                acc = fmaf(q4.x, kT[(d + 0) * NWIN + j], acc);
                acc = fmaf(q4.y, kT[(d + 1) * NWIN + j], acc);
                acc = fmaf(q4.z, kT[(d + 2) * NWIN + j], acc);
                acc = fmaf(q4.w, kT[(d + 3) * NWIN + j], acc);
            }
            const int ri = rel_index[idx];
            acc += bias_tab[ri * NH + h];
            acc += mask[(wmask * NWIN + i) * NWIN + j];
            attn[idx] = acc;
        }
        __syncthreads();

        // ---- phase 3b: row softmax (one thread per row) ----
        if (t < NWIN) {
            float* row = attn + t * NWIN;
            float m = -1e30f;
            for (int j = 0; j < NWIN; ++j) m = fmaxf(m, row[j]);
            float s = 0.f;
            for (int j = 0; j < NWIN; ++j) { float e = __expf(row[j] - m); row[j] = e; s += e; }
            const float rs = 1.f / s;
            for (int j = 0; j < NWIN; ++j) row[j] *= rs;
        }
        __syncthreads();

        // ---- phase 4: outs[:, h*32:+32] = attn @ v  (stored bf16) ----
        for (int idx = t; idx < NWIN * HD; idx += 256) {
            const int i = idx >> 5, d = idx & 31;
            float acc = 0.f;
            const float* arow = attn + i * NWIN;
            #pragma unroll 7
            for (int j = 0; j < NWIN; ++j)
                acc = fmaf(arow[j], vs[j * HD + d], acc);
            outs[i * DIM + h * HD + d] = f2bf(acc);
        }
        __syncthreads();  // protects qs/kT/vs overwrite next head + outs reads in phase 5
    }

    // ---- phase 5: final projection ----
    const size_t obase = (size_t)b * (NWIN * DIM);
    for (int idx = t; idx < NWIN * DIM; idx += 256) {
        const int i = idx >> 7, c = idx & 127;
        float acc = proj_b[c];
        #pragma unroll 8
        for (int cp = 0; cp < DIM; cp += 4) {
            uint2 xu = *(const uint2*)(outs + i * DIM + cp);
            acc = fmaf(bf_lo(xu.x), proj_w[(cp + 0) * DIM + c], acc);
            acc = fmaf(bf_hi(xu.x), proj_w[(cp + 1) * DIM + c], acc);
            acc = fmaf(bf_lo(xu.y), proj_w[(cp + 2) * DIM + c], acc);
            acc = fmaf(bf_hi(xu.y), proj_w[(cp + 3) * DIM + c], acc);
        }
        out[obase + idx] = acc;
    }
}

extern "C" void kernel_launch(void* const* d_in, const int* in_sizes, int n_in,
                              void* d_out, int out_size, void* d_ws, size_t ws_size,
                              hipStream_t stream) {
    const int B = in_sizes[0] / (NWIN * DIM);  // 4096 windows
    winattn_kernel<<<B, 256, 0, stream>>>(
        (const float*)d_in[0],  // x
        (const float*)d_in[1],  // mask
        (const float*)d_in[2],  // qkv_w
        (const float*)d_in[3],  // qkv_b
        (const float*)d_in[4],  // proj_w
        (const float*)d_in[5],  // proj_b
        (const float*)d_in[6],  // rel_bias_table
        (const int*)d_in[7],    // rel_index
        (float*)d_out);
}

// Round 3
// 580.152 us; speedup vs baseline: 2.9822x; 2.9822x over previous
//
#include <hip/hip_runtime.h>
#include <hip/hip_bf16.h>

#define NWIN 49
#define DIM  128
#define NH   4
#define HD   32
#define SCALE 0.17677669529663687f

using short8 = __attribute__((ext_vector_type(8))) short;
using f32x4  = __attribute__((ext_vector_type(4))) float;

union Frag { uint4 u; short8 s; };

static __device__ __forceinline__ unsigned short f2bf(float f) {
    union { float f; unsigned i; } v; v.f = f;
    unsigned r = v.i + 0x7fffu + ((v.i >> 16) & 1u);   // RNE
    return (unsigned short)(r >> 16);
}

static __device__ __forceinline__ short8 ld8(const unsigned short* p) {
    Frag fr; fr.u = *(const uint4*)p; return fr.s;
}

// ---- prep: transpose+convert weights to bf16, pre-gather rel-pos bias ----
__global__ __launch_bounds__(256) void prep_kernel(
    const float* __restrict__ qkv_w,    // [128,384]
    const float* __restrict__ proj_w,   // [128,128]
    const float* __restrict__ bias_tab, // [169,4]
    const int*   __restrict__ rel_index,// [49,49]
    unsigned short* __restrict__ wqkvT, // [384,128] bf16
    unsigned short* __restrict__ projT, // [128,128] bf16
    float*          __restrict__ biasHIJ) // [4,49,49]
{
    int tid = blockIdx.x * 256 + threadIdx.x;
    if (tid < 49152) {
        int n = tid >> 7, k = tid & 127;
        wqkvT[tid] = f2bf(qkv_w[k * 384 + n]);
    } else if (tid < 65536) {
        int t2 = tid - 49152;
        int n = t2 >> 7, k = t2 & 127;
        projT[t2] = f2bf(proj_w[k * 128 + n]);
    } else if (tid < 65536 + NH * 2401) {
        int idx = tid - 65536;
        int h = idx / 2401, ij = idx % 2401;
        biasHIJ[idx] = bias_tab[rel_index[ij] * NH + h];
    }
}

// LDS pool offsets (bytes)
#define OFF_XS   0        // ushort [64][136]  17408
#define OFF_OS   17408    // ushort [64][136]  17408
#define OFF_QH   34816    // ushort [64][40]    5120
#define OFF_KH   39936    // ushort [64][40]    5120
#define OFF_PS   34816    // ushort [64][72]    9216 (aliases QH+KH)
#define OFF_VT   45056    // ushort [32][72]    4608
#define OFF_ATT  49664    // float  [64][53]   13568
#define OFF_PMX  63232    // float  [64][4]     1024
#define OFF_RSM  64256    // float  [64]         256
#define OFF_RMX  64512    // float  [64]         256
#define POOL_SZ  64768

__global__ __launch_bounds__(256) void winattn_kernel(
    const float* __restrict__ x,        // [4096,49,128]
    const float* __restrict__ mask,     // [64,49,49]
    const float* __restrict__ qkv_b,    // [384]
    const float* __restrict__ proj_b,   // [128]
    const unsigned short* __restrict__ wqkvT,  // [384,128] bf16
    const unsigned short* __restrict__ projT,  // [128,128] bf16
    const float* __restrict__ biasHIJ,  // [4,49,49]
    float*       __restrict__ out)      // [4096,49,128]
{
    __shared__ __align__(16) char pool[POOL_SZ];
    unsigned short* XS = (unsigned short*)(pool + OFF_XS);
    unsigned short* OS = (unsigned short*)(pool + OFF_OS);
    unsigned short* QH = (unsigned short*)(pool + OFF_QH);
    unsigned short* KH = (unsigned short*)(pool + OFF_KH);
    unsigned short* PS = (unsigned short*)(pool + OFF_PS);
    unsigned short* VT = (unsigned short*)(pool + OFF_VT);
    float* ATT = (float*)(pool + OFF_ATT);
    float* PMX = (float*)(pool + OFF_PMX);
    float* RSM = (float*)(pool + OFF_RSM);
    float* RMX = (float*)(pool + OFF_RMX);

    const int b = blockIdx.x;
    const int t = threadIdx.x;
    const int w = t >> 6;        // wave 0..3
    const int lane = t & 63;
    const int q = lane >> 4;     // quad 0..3
    const int l16 = lane & 15;
    const int wm = b & 63;       // window-in-batch for mask

    // ---- stage X -> bf16 LDS [64][136] (rows >=49 zero) ----
    for (int c = t; c < 1024; c += 256) {      // 8-elem chunks
        int row = c >> 4, g = c & 15;
        unsigned short* dst = XS + row * 136 + g * 8;
        uint2 p0, p1;
        if (row < NWIN) {
            const float4* src = (const float4*)(x + (size_t)b * (NWIN * DIM) + row * DIM + g * 8);
            float4 f0 = src[0], f1 = src[1];
            p0.x = (unsigned)f2bf(f0.x) | ((unsigned)f2bf(f0.y) << 16);
            p0.y = (unsigned)f2bf(f0.z) | ((unsigned)f2bf(f0.w) << 16);
            p1.x = (unsigned)f2bf(f1.x) | ((unsigned)f2bf(f1.y) << 16);
            p1.y = (unsigned)f2bf(f1.z) | ((unsigned)f2bf(f1.w) << 16);
        } else { p0.x = p0.y = p1.x = p1.y = 0u; }
        *(uint2*)dst = p0;
        *(uint2*)(dst + 4) = p1;
    }
    __syncthreads();

    for (int h = 0; h < NH; ++h) {
        // ---- GEMM1: QKV tiles for head h (24 jobs: s{q,k,v} x n{0,1} x mt{0..3}) ----
        for (int job = w; job < 24; job += 4) {
            const int mt = job & 3, sn = job >> 2, s = sn >> 1, nn = sn & 1;
            const int colbase = s * 128 + h * 32 + nn * 16;
            f32x4 acc = {0.f, 0.f, 0.f, 0.f};
            const unsigned short* arow = XS + (mt * 16 + l16) * 136 + q * 8;
            const unsigned short* brow = wqkvT + (size_t)(colbase + l16) * 128 + q * 8;
            #pragma unroll
            for (int ks = 0; ks < 4; ++ks) {
                short8 a = ld8(arow + ks * 32);
                short8 bf = ld8(brow + ks * 32);
                acc = __builtin_amdgcn_mfma_f32_16x16x32_bf16(a, bf, acc, 0, 0, 0);
            }
            const float bias = qkv_b[colbase + l16];
            const int cl = nn * 16 + l16;
            #pragma unroll
            for (int r = 0; r < 4; ++r) {
                const int row = mt * 16 + q * 4 + r;
                const float val = acc[r] + bias;
                if (s == 0)      QH[row * 40 + cl] = f2bf(val * SCALE);
                else if (s == 1) KH[row * 40 + cl] = f2bf(val);
                else             VT[cl * 72 + row] = f2bf(val);
            }
        }
        __syncthreads();

        // ---- S = Q K^T + bias + mask (16 tiles) ----
        for (int job = w; job < 16; job += 4) {
            const int mt = job >> 2, nt = job & 3;
            short8 a = ld8(QH + (mt * 16 + l16) * 40 + q * 8);
            short8 bf = ld8(KH + (nt * 16 + l16) * 40 + q * 8);
            f32x4 acc = {0.f, 0.f, 0.f, 0.f};
            acc = __builtin_amdgcn_mfma_f32_16x16x32_bf16(a, bf, acc, 0, 0, 0);
            const int j = nt * 16 + l16;
            if (j < NWIN) {
                #pragma unroll
                for (int r = 0; r < 4; ++r) {
                    const int i = mt * 16 + q * 4 + r;
                    if (i < NWIN)
                        ATT[i * 53 + j] = acc[r] + biasHIJ[h * 2401 + i * 49 + j]
                                                 + mask[wm * 2401 + i * 49 + j];
                }
            }
        }
        __syncthreads();

        // ---- softmax: 4 threads per row ----
        {
            const int row = t >> 2, p = t & 3;
            if (row < NWIN) {
                const int j0 = p * 13, j1 = (p == 3) ? 49 : (j0 + 13);
                float m = -1e30f;
                for (int j = j0; j < j1; ++j) m = fmaxf(m, ATT[row * 53 + j]);
                PMX[row * 4 + p] = m;
            }
        }
        __syncthreads();
        if (t < NWIN)
            RMX[t] = fmaxf(fmaxf(PMX[t * 4], PMX[t * 4 + 1]), fmaxf(PMX[t * 4 + 2], PMX[t * 4 + 3]));
        __syncthreads();
        {
            const int row = t >> 2, p = t & 3;
            if (row < NWIN) {
                const int j0 = p * 13, j1 = (p == 3) ? 49 : (j0 + 13);
                const float m = RMX[row];
                float s = 0.f;
                for (int j = j0; j < j1; ++j) {
                    float e = __expf(ATT[row * 53 + j] - m);
                    PS[row * 72 + j] = f2bf(e);
                    s += e;
                }
                PMX[row * 4 + p] = s;
                if (p == 3)
                    for (int j = 49; j < 64; ++j) PS[row * 72 + j] = 0;
            } else if (row < 64 && p == 0) {
                for (int j = 0; j < 64; ++j) PS[row * 72 + j] = 0;  // pad rows: exact zeros
            }
        }
        __syncthreads();
        if (t < 64)
            RSM[t] = (t < NWIN)
                ? 1.f / (PMX[t * 4] + PMX[t * 4 + 1] + PMX[t * 4 + 2] + PMX[t * 4 + 3])
                : 0.f;
        __syncthreads();

        // ---- O_h = P V (8 tiles, K=64) ----
        for (int job = w; job < 8; job += 4) {
            const int mt = job >> 1, nt = job & 1;
            f32x4 acc = {0.f, 0.f, 0.f, 0.f};
            #pragma unroll
            for (int ks = 0; ks < 2; ++ks) {
                short8 a = ld8(PS + (mt * 16 + l16) * 72 + ks * 32 + q * 8);
                short8 bf = ld8(VT + (nt * 16 + l16) * 72 + ks * 32 + q * 8);
                acc = __builtin_amdgcn_mfma_f32_16x16x32_bf16(a, bf, acc, 0, 0, 0);
            }
            const int d = h * 32 + nt * 16 + l16;
            #pragma unroll
            for (int r = 0; r < 4; ++r) {
                const int row = mt * 16 + q * 4 + r;
                OS[row * 136 + d] = f2bf(acc[r] * RSM[row]);
            }
        }
        __syncthreads();   // QH/KH/VT/ATT rewritten next head
    }

    // ---- final projection: out = O @ proj_w + proj_b (32 tiles) ----
    for (int job = w; job < 32; job += 4) {
        const int mt = job >> 3, nt = job & 7;
        f32x4 acc = {0.f, 0.f, 0.f, 0.f};
        const unsigned short* arow = OS + (mt * 16 + l16) * 136 + q * 8;
        const unsigned short* brow = projT + (size_t)(nt * 16 + l16) * 128 + q * 8;
        #pragma unroll
        for (int ks = 0; ks < 4; ++ks) {
            short8 a = ld8(arow + ks * 32);
            short8 bf = ld8(brow + ks * 32);
            acc = __builtin_amdgcn_mfma_f32_16x16x32_bf16(a, bf, acc, 0, 0, 0);
        }
        const int col = nt * 16 + l16;
        const float pb = proj_b[col];
        #pragma unroll
        for (int r = 0; r < 4; ++r) {
            const int row = mt * 16 + q * 4 + r;
            if (row < NWIN)
                out[(size_t)b * (NWIN * DIM) + row * 128 + col] = acc[r] + pb;
        }
    }
}

extern "C" void kernel_launch(void* const* d_in, const int* in_sizes, int n_in,
                              void* d_out, int out_size, void* d_ws, size_t ws_size,
                              hipStream_t stream) {
    const int B = in_sizes[0] / (NWIN * DIM);  // 4096 windows
    unsigned short* wqkvT = (unsigned short*)d_ws;                       //  98304 B
    unsigned short* projT = (unsigned short*)((char*)d_ws + 98304);      //  32768 B
    float*          biasHIJ = (float*)((char*)d_ws + 131072);            //  38416 B

    prep_kernel<<<294, 256, 0, stream>>>(
        (const float*)d_in[2],  // qkv_w
        (const float*)d_in[4],  // proj_w
        (const float*)d_in[6],  // rel_bias_table
        (const int*)d_in[7],    // rel_index
        wqkvT, projT, biasHIJ);

    winattn_kernel<<<B, 256, 0, stream>>>(
        (const float*)d_in[0],  // x
        (const float*)d_in[1],  // mask
        (const float*)d_in[3],  // qkv_b
        (const float*)d_in[5],  // proj_b
        wqkvT, projT, biasHIJ,
        (float*)d_out);
}

// Round 4
// 356.495 us; speedup vs baseline: 4.8531x; 1.6274x over previous
//
#include <hip/hip_runtime.h>

#define NWIN 49
#define DIM  128
#define NH   4
#define HD   32
#define SCALE 0.17677669529663687f

using short8 = __attribute__((ext_vector_type(8))) short;
using f32x4  = __attribute__((ext_vector_type(4))) float;

union Frag { uint4 u; short8 s; };

static __device__ __forceinline__ short8 ld8(const unsigned short* p) {
    Frag fr; fr.u = *(const uint4*)p; return fr.s;
}
static __device__ __forceinline__ unsigned short f2bf(float f) {
    union { float f; unsigned i; } v; v.f = f;
    unsigned r = v.i + 0x7fffu + ((v.i >> 16) & 1u);   // RNE
    return (unsigned short)(r >> 16);
}

// ---- prep: bf16 transposed weights + precombined bias+mask table ----
__global__ __launch_bounds__(256) void prep_kernel(
    const float* __restrict__ qkv_w,    // [128,384]
    const float* __restrict__ proj_w,   // [128,128]
    const float* __restrict__ mask,     // [64,49,49]
    const float* __restrict__ bias_tab, // [169,4]
    const int*   __restrict__ rel_index,// [49,49]
    unsigned short* __restrict__ wqkvT, // [384,128] bf16
    unsigned short* __restrict__ projT, // [128,128] bf16
    float*          __restrict__ BM)    // [64,4,49,49] fp32: mask+bias
{
    int tid = blockIdx.x * 256 + threadIdx.x;
    if (tid < 49152) {
        int n = tid >> 7, k = tid & 127;
        wqkvT[tid] = f2bf(qkv_w[k * 384 + n]);
    } else if (tid < 65536) {
        int t2 = tid - 49152;
        int n = t2 >> 7, k = t2 & 127;
        projT[t2] = f2bf(proj_w[k * 128 + n]);
    } else if (tid < 65536 + 64 * NH * 2401) {
        int idx = tid - 65536;
        int wh = idx / 2401, ij = idx % 2401;
        int wm = wh >> 2, h = wh & 3;
        BM[idx] = mask[wm * 2401 + ij] + bias_tab[rel_index[ij] * NH + h];
    }
}

// LDS layout (bytes):
//  [0, 13328)            XS [49][136] ushort  -- aliased by OS after sync #2
//  [13328 + w*12448 ...) per-wave pool:
//      +0     VT [32][72] ushort (4608)
//      +4608  QH [49][40] ushort (3920)   } aliased by PS [49][72] (7056)
//      +8528  KH [49][40] ushort (3920)   }   after S-tile MFMAs complete
//  pad to 65168 so spill-reads of pad rows (49..63) stay inside the pool.
#define XS_STRIDE 136
#define WPOOL_OFF 13328
#define WPOOL_SZ  12448
#define QH_OFF    4608
#define KH_OFF    8528
#define PS_OFF    4608
#define POOL_SZ   65168

__global__ __launch_bounds__(256) void winattn_kernel(
    const float* __restrict__ x,        // [4096,49,128]
    const float* __restrict__ qkv_b,    // [384]
    const float* __restrict__ proj_b,   // [128]
    const unsigned short* __restrict__ wqkvT,  // [384,128] bf16
    const unsigned short* __restrict__ projT,  // [128,128] bf16
    const float* __restrict__ BM,       // [64,4,49,49]
    float*       __restrict__ out)      // [4096,49,128]
{
    __shared__ __align__(16) char pool[POOL_SZ];
    unsigned short* XS = (unsigned short*)pool;   // also OS after sync #2

    const int b = blockIdx.x;
    const int t = threadIdx.x;
    const int w = t >> 6;        // wave = head
    const int lane = t & 63;
    const int q = lane >> 4;     // quad 0..3
    const int l16 = lane & 15;
    const int wm = b & 63;
    const int h = w;

    char* wp = pool + WPOOL_OFF + w * WPOOL_SZ;
    unsigned short* VT = (unsigned short*)wp;              // [32][72] V^T
    unsigned short* QH = (unsigned short*)(wp + QH_OFF);   // [49][40]
    unsigned short* KH = (unsigned short*)(wp + KH_OFF);   // [49][40]
    unsigned short* PS = (unsigned short*)(wp + PS_OFF);   // [49][72], aliases QH+KH

    // ---- stage X -> bf16 LDS [49][136] ----
    for (int c = t; c < NWIN * 16; c += 256) {
        const int row = c >> 4, g = c & 15;
        const float4* src = (const float4*)(x + (size_t)b * (NWIN * DIM) + row * DIM + g * 8);
        float4 f0 = src[0], f1 = src[1];
        uint4 p;
        p.x = (unsigned)f2bf(f0.x) | ((unsigned)f2bf(f0.y) << 16);
        p.y = (unsigned)f2bf(f0.z) | ((unsigned)f2bf(f0.w) << 16);
        p.z = (unsigned)f2bf(f1.x) | ((unsigned)f2bf(f1.y) << 16);
        p.w = (unsigned)f2bf(f1.z) | ((unsigned)f2bf(f1.w) << 16);
        *(uint4*)(XS + row * XS_STRIDE + g * 8) = p;
    }
    __syncthreads();   // sync #1

    // ---- phase B: QKV for head h (wave-private outputs) ----
    #pragma unroll
    for (int job = 0; job < 24; ++job) {
        const int mt = job & 3, sn = job >> 2, s = sn >> 1, nn = sn & 1;
        const int colbase = s * 128 + h * 32 + nn * 16;
        f32x4 acc = {0.f, 0.f, 0.f, 0.f};
        const unsigned short* arow = XS + (mt * 16 + l16) * XS_STRIDE + q * 8;
        const unsigned short* brow = wqkvT + (size_t)(colbase + l16) * 128 + q * 8;
        #pragma unroll
        for (int ks = 0; ks < 4; ++ks)
            acc = __builtin_amdgcn_mfma_f32_16x16x32_bf16(ld8(arow + ks * 32),
                                                          ld8(brow + ks * 32), acc, 0, 0, 0);
        const float bias = qkv_b[colbase + l16];
        const int cl = nn * 16 + l16;
        #pragma unroll
        for (int r = 0; r < 4; ++r) {
            const int row = mt * 16 + q * 4 + r;
            const float val = acc[r] + bias;
            if (s == 0)      { if (row < NWIN) QH[row * 40 + cl] = f2bf(val * SCALE); }
            else if (s == 1) { if (row < NWIN) KH[row * 40 + cl] = f2bf(val); }
            else             VT[cl * 72 + row] = f2bf(val);  // row<=63 < 72: in-pad, safe
        }
    }
    __syncthreads();   // sync #2: all waves done reading XS -> OS may alias it

    // ---- phase C: S = Q K^T (registers), softmax (registers), P -> LDS ----
    float sv[4][4][4];  // [mt][nt][r]
    {
        short8 bfr[4];
        #pragma unroll
        for (int nt = 0; nt < 4; ++nt)
            bfr[nt] = ld8(KH + (nt * 16 + l16) * 40 + q * 8);
        #pragma unroll
        for (int mt = 0; mt < 4; ++mt) {
            short8 a = ld8(QH + (mt * 16 + l16) * 40 + q * 8);
            #pragma unroll
            for (int nt = 0; nt < 4; ++nt) {
                f32x4 acc = {0.f, 0.f, 0.f, 0.f};
                acc = __builtin_amdgcn_mfma_f32_16x16x32_bf16(a, bfr[nt], acc, 0, 0, 0);
                #pragma unroll
                for (int r = 0; r < 4; ++r) sv[mt][nt][r] = acc[r];
            }
        }
    }
    // add combined bias+mask; pad cols -> -inf
    {
        const float* bm = BM + (size_t)(wm * NH + h) * 2401;
        #pragma unroll
        for (int mt = 0; mt < 4; ++mt)
            #pragma unroll
            for (int r = 0; r < 4; ++r) {
                const int i = mt * 16 + q * 4 + r;
                const float* bmr = bm + i * 49;
                #pragma unroll
                for (int nt = 0; nt < 4; ++nt) {
                    const int j = nt * 16 + l16;
                    if (j >= NWIN)      sv[mt][nt][r] = -1e30f;
                    else if (i < NWIN)  sv[mt][nt][r] += bmr[j];
                    // i>=49: garbage, confined to never-stored rows
                }
            }
    }
    // softmax per row, 1/sum folded into P
    #pragma unroll
    for (int mt = 0; mt < 4; ++mt)
        #pragma unroll
        for (int r = 0; r < 4; ++r) {
            float m = fmaxf(fmaxf(sv[mt][0][r], sv[mt][1][r]),
                            fmaxf(sv[mt][2][r], sv[mt][3][r]));
            m = fmaxf(m, __shfl_xor(m, 1));
            m = fmaxf(m, __shfl_xor(m, 2));
            m = fmaxf(m, __shfl_xor(m, 4));
            m = fmaxf(m, __shfl_xor(m, 8));
            float sum = 0.f;
            #pragma unroll
            for (int nt = 0; nt < 4; ++nt) {
                float e = __expf(sv[mt][nt][r] - m);
                sv[mt][nt][r] = e;
                sum += e;
            }
            sum += __shfl_xor(sum, 1);
            sum += __shfl_xor(sum, 2);
            sum += __shfl_xor(sum, 4);
            sum += __shfl_xor(sum, 8);
            const float rs = 1.f / sum;
            const int i = mt * 16 + q * 4 + r;
            if (i < NWIN) {
                #pragma unroll
                for (int nt = 0; nt < 4; ++nt)
                    PS[i * 72 + nt * 16 + l16] = f2bf(sv[mt][nt][r] * rs);
            }
        }

    // ---- phase D: O_h = P V (wave-local; no sync needed) ----
    #pragma unroll
    for (int nt2 = 0; nt2 < 2; ++nt2) {
        short8 bv0 = ld8(VT + (nt2 * 16 + l16) * 72 + q * 8);
        short8 bv1 = ld8(VT + (nt2 * 16 + l16) * 72 + 32 + q * 8);
        #pragma unroll
        for (int mt = 0; mt < 4; ++mt) {
            f32x4 acc = {0.f, 0.f, 0.f, 0.f};
            acc = __builtin_amdgcn_mfma_f32_16x16x32_bf16(
                ld8(PS + (mt * 16 + l16) * 72 + q * 8), bv0, acc, 0, 0, 0);
            acc = __builtin_amdgcn_mfma_f32_16x16x32_bf16(
                ld8(PS + (mt * 16 + l16) * 72 + 32 + q * 8), bv1, acc, 0, 0, 0);
            #pragma unroll
            for (int r = 0; r < 4; ++r) {
                const int row = mt * 16 + q * 4 + r;
                if (row < NWIN)
                    XS[row * XS_STRIDE + h * 32 + nt2 * 16 + l16] = f2bf(acc[r]);  // OS
            }
        }
    }
    __syncthreads();   // sync #3: full O assembled

    // ---- phase E: out = O @ proj_w + proj_b ----
    for (int job = w; job < 32; job += 4) {
        const int mt = job >> 3, nt = job & 7;
        f32x4 acc = {0.f, 0.f, 0.f, 0.f};
        const unsigned short* arow = XS + (mt * 16 + l16) * XS_STRIDE + q * 8;
        const unsigned short* brow = projT + (size_t)(nt * 16 + l16) * 128 + q * 8;
        #pragma unroll
        for (int ks = 0; ks < 4; ++ks)
            acc = __builtin_amdgcn_mfma_f32_16x16x32_bf16(ld8(arow + ks * 32),
                                                          ld8(brow + ks * 32), acc, 0, 0, 0);
        const int col = nt * 16 + l16;
        const float pb = proj_b[col];
        #pragma unroll
        for (int r = 0; r < 4; ++r) {
            const int row = mt * 16 + q * 4 + r;
            if (row < NWIN)
                out[(size_t)b * (NWIN * DIM) + row * 128 + col] = acc[r] + pb;
        }
    }
}

extern "C" void kernel_launch(void* const* d_in, const int* in_sizes, int n_in,
                              void* d_out, int out_size, void* d_ws, size_t ws_size,
                              hipStream_t stream) {
    const int B = in_sizes[0] / (NWIN * DIM);  // 4096 windows
    unsigned short* wqkvT = (unsigned short*)d_ws;                   //    98304 B
    unsigned short* projT = (unsigned short*)((char*)d_ws + 98304);  //    32768 B
    float*          BM    = (float*)((char*)d_ws + 131072);          //  2458624 B

    prep_kernel<<<2657, 256, 0, stream>>>(
        (const float*)d_in[2],  // qkv_w
        (const float*)d_in[4],  // proj_w
        (const float*)d_in[1],  // mask
        (const float*)d_in[6],  // rel_bias_table
        (const int*)d_in[7],    // rel_index
        wqkvT, projT, BM);

    winattn_kernel<<<B, 256, 0, stream>>>(
        (const float*)d_in[0],  // x
        (const float*)d_in[3],  // qkv_b
        (const float*)d_in[5],  // proj_b
        wqkvT, projT, BM,
        (float*)d_out);
}